// Round 5
// baseline (344.786 us; speedup 1.0000x reference)
//
#include <hip/hip_runtime.h>
#include <hip/hip_bf16.h>

typedef short s16;
typedef __attribute__((ext_vector_type(8))) short bf16x8;  // 8 bf16 = 4 VGPR (MFMA A/B frag)
typedef __attribute__((ext_vector_type(4))) float f32x4;   // MFMA C/D frag

// ---------------- helpers ----------------
__device__ __forceinline__ s16 f2bf(float f) {
  unsigned u = __builtin_bit_cast(unsigned, f);
  unsigned r = (u + 0x7FFFu + ((u >> 16) & 1u)) >> 16;
  return (s16)r;
}

__device__ __forceinline__ float hsig(float x) {
  return fminf(fmaxf(0.2f * x + 0.5f, 0.0f), 1.0f);
}

// ---------------- prep kernel (all weight transposes in one launch) ----------------
__global__ void wprep_kernel(const float* __restrict__ rk0, const float* __restrict__ k1,
                             const float* __restrict__ rk1, const float* __restrict__ k0,
                             s16* __restrict__ w0t, s16* __restrict__ w1t,
                             s16* __restrict__ w2t, s16* __restrict__ k0t) {
  int idx = blockIdx.x * 256 + threadIdx.x;
  const int n1 = 9 * 256 * 64;  // 147456
  if (idx < 3 * n1) {
    int which = idx / n1;
    int r = idx - which * n1;
    int ic = r & 63;
    int oc = (r >> 6) & 255;
    int tap = r >> 14;
    const float* src = (which == 0) ? rk0 : (which == 1) ? k1 : rk1;
    s16* dst = (which == 0) ? w0t : (which == 1) ? w1t : w2t;
    dst[r] = f2bf(src[(tap * 64 + ic) * 256 + oc]);
  } else if (idx < 3 * n1 + 8192) {
    int r = idx - 3 * n1;
    int kk = r & 31;
    int oc = r >> 5;
    k0t[r] = (kk < 9) ? f2bf(k0[kk * 256 + oc]) : (s16)0;
  }
}

// ---------------- ConvLSTM cell kernel ----------------
// Block: 512 threads = 8 waves, 2 blocks/CU. Tile: M=128 pixels (2 output rows),
// N=256 (all 4 gates). Wave (mh = wave>>2 in 0..1, g = wave&3): output row y0+mh,
// oc {j*64+g*16+0..15} j=0..3 -> all 4 gates of (pixel, f) lane-local.
// A tile: ONE source, 4 rows x padded stride 66, XOR-swizzled; layer-1 runs two
// sequential passes (src0 taps, then RESTAGE, src1 taps) accumulating into acc.
// W: per half-tap stage 16 KB slice [icg][oc][8], double-buffered LDS via
// global_load_lds (2 x 16B per thread). Per stage: vmcnt(0) [only the 1-stage-old
// load is outstanding] -> s_barrier -> issue stage u+2 -> ds_read stage u+1 W frags
// -> MFMA stage u from registers (setprio 1). One barrier per stage.
// grid: 1024 blocks: b = blk>>5, y0 = (blk&31)*2.
#define PXS 66
#define ROWSZ (PXS * 64)             // 4224 elements per tile row
#define ASZ (4 * ROWSZ)              // 16896 elements (one source tile)

template <bool F32>
__device__ __forceinline__ bf16x8 load_conv8(const void* src, long off) {
  if constexpr (F32) {
    const float* p = (const float*)src + off;
    float4 v0 = *reinterpret_cast<const float4*>(p);
    float4 v1 = *reinterpret_cast<const float4*>(p + 4);
    bf16x8 r;
    r[0] = f2bf(v0.x); r[1] = f2bf(v0.y); r[2] = f2bf(v0.z); r[3] = f2bf(v0.w);
    r[4] = f2bf(v1.x); r[5] = f2bf(v1.y); r[6] = f2bf(v1.z); r[7] = f2bf(v1.w);
    return r;
  } else {
    return *reinterpret_cast<const bf16x8*>((const s16*)src + off);
  }
}

template <bool F32>
__device__ __forceinline__ void stage_src(s16* a_lds, const void* src, int b, int y0, int tid) {
  #pragma unroll
  for (int i = 0; i < 4; ++i) {
    int c   = tid + i * 512;        // 0..2047 16B-chunks
    int row = c >> 9;               // 0..3
    int px  = (c >> 3) & 63;
    int cb  = c & 7;
    int y   = y0 - 1 + row;
    int xp  = px + 1;
    bf16x8 v = {};
    if ((unsigned)y < 64u)
      v = load_conv8<F32>(src, ((long)(b * 64 + y) * 64 + px) * 64 + cb * 8);
    *reinterpret_cast<bf16x8*>(a_lds + (row * PXS + xp) * 64 + ((cb ^ (xp & 7)) * 8)) = v;
  }
  // zero x-border columns (xp = 0, 65)
  if (tid < 64) {
    int row = tid >> 4;
    int xp  = ((tid >> 3) & 1) ? 65 : 0;
    int cb  = tid & 7;
    bf16x8 z = {};
    *reinterpret_cast<bf16x8*>(a_lds + (row * PXS + xp) * 64 + cb * 8) = z;
  }
}

template <int NSRC, bool XPATH, bool S0F32, bool S1F32>
__global__ __launch_bounds__(512, 4) void cell_kernel(
    const void* __restrict__ src0,  // [B,64,64,64] bf16 or fp32
    const void* __restrict__ src1,  // [B,64,64,64] bf16 or fp32 (NSRC==2)
    const s16* __restrict__ w0,     // [9][256][64] bf16
    const s16* __restrict__ w1,     // [9][256][64] bf16 (NSRC==2)
    const float* __restrict__ xin,  // [B,64,64] fp32 (XPATH)
    const s16* __restrict__ k0t,    // [256][32] bf16 (XPATH)
    const float* __restrict__ bias, // [256]
    const float* __restrict__ c_old,// [B,64,64,64] fp32
    float* __restrict__ h_out,
    float* __restrict__ c_out,
    s16* __restrict__ hb_out)       // bf16 copy of h (nullable)
{
  __shared__ __align__(16) s16 a_lds[ASZ];       // 33792 B (one source at a time)
  __shared__ __align__(16) s16 w_lds[2][8192];   // 2 x 16 KB
  __shared__ float x_lds[XPATH ? 256 : 1];

  const int tid = threadIdx.x;
  const int b  = blockIdx.x >> 5;
  const int y0 = (blockIdx.x & 31) << 1;

  const int wave = tid >> 6;
  const int lane = tid & 63;
  const int g    = wave & 3;
  const int mh   = wave >> 2;   // 0..1: output row within the 2-row tile
  const int l15  = lane & 15;
  const int l4   = lane >> 4;

  constexpr int NST = NSRC * 18;

  // W stage issue: 2 x 16B global_load_lds per thread (16 KB slice / 512 threads)
  auto issueW = [&](int u) {
    int t2 = u >> 1, k = u & 1;
    int si  = (NSRC == 2 && t2 >= 9) ? 1 : 0;
    int tap = t2 - 9 * si;
    const s16* wt = (si ? w1 : w0) + tap * 16384 + k * 32;
    char* wl = (char*)(&w_lds[u & 1][0]);
    // chunk c = tid: elem off (c&255)*64 + (c>>8)*8 ; LDS dest = wave*1024 + lane*16
    __builtin_amdgcn_global_load_lds(
        (const __attribute__((address_space(1))) void*)(wt + (tid & 255) * 64 + (tid >> 8) * 8),
        (__attribute__((address_space(3))) void*)(wl + (tid >> 6) * 1024), 16, 0, 0);
    // chunk c2 = tid + 512: elem off (c&255)*64 + ((tid>>8)+2)*8 ; dest = 8192 + wave*1024
    __builtin_amdgcn_global_load_lds(
        (const __attribute__((address_space(1))) void*)(wt + (tid & 255) * 64 + ((tid >> 8) + 2) * 8),
        (__attribute__((address_space(3))) void*)(wl + 8192 + (tid >> 6) * 1024), 16, 0, 0);
  };

  auto readW = [&](bf16x8 (&wf)[4], int slot) {
    const char* wb = (const char*)(&w_lds[slot][0]) + l4 * 4096;
    #pragma unroll
    for (int j = 0; j < 4; ++j) {
      int oc = j * 64 + g * 16 + l15;
      wf[j] = *reinterpret_cast<const bf16x8*>(wb + oc * 16);
    }
  };

  f32x4 acc[4][4] = {};  // [m-frag][gate j]
  bf16x8 wfA[4], wfB[4];

  auto body = [&](bf16x8 (&wfC)[4], bf16x8 (&wfN)[4], int u) {
    asm volatile("s_waitcnt vmcnt(0)" ::: "memory");  // only stage-(u+1) load outstanding
    __builtin_amdgcn_s_barrier();                     // slot (u+1)&1 now valid block-wide
    if (u + 2 < NST) issueW(u + 2);                   // overwrites slot u&1 (readers done @u-1)
    if (u + 1 < NST) readW(wfN, (u + 1) & 1);         // next-stage W frags under this stage's MFMA
    int t2 = u >> 1, k = u & 1;
    int tap = (t2 >= 9) ? t2 - 9 : t2;
    int dy = tap / 3, dx = tap - dy * 3;
    const char* lb = (const char*)a_lds + (mh + dy) * (ROWSZ * 2);
    __builtin_amdgcn_s_setprio(1);
    #pragma unroll
    for (int m = 0; m < 4; ++m) {
      int xq   = m * 16 + l15 + dx;
      int boff = xq * 128 + (((k << 6) | (l4 << 4)) ^ ((xq & 7) << 4));
      bf16x8 a = *reinterpret_cast<const bf16x8*>(lb + boff);
      #pragma unroll
      for (int j = 0; j < 4; ++j)
        acc[m][j] = __builtin_amdgcn_mfma_f32_16x16x32_bf16(a, wfC[j], acc[m][j], 0, 0, 0);
    }
    __builtin_amdgcn_s_setprio(0);
  };

  // ---- pass 0 staging ----
  stage_src<S0F32>(a_lds, src0, b, y0, tid);
  if (XPATH) {
    if (tid < 256) {
      int row = tid >> 6, px = tid & 63;
      int y = y0 - 1 + row;
      x_lds[tid] = ((unsigned)y < 64u) ? xin[(b * 64 + y) * 64 + px] : 0.0f;
    }
  }
  issueW(0);
  issueW(1);
  __syncthreads();   // staging + W slots 0,1 all visible

  // ---- x-conv as one zero-padded K=32 MFMA step (layer 0 only) ----
  if (XPATH) {
    bf16x8 bx[4];
    #pragma unroll
    for (int j = 0; j < 4; ++j) {
      int oc = j * 64 + g * 16 + l15;
      bx[j] = *reinterpret_cast<const bf16x8*>(k0t + oc * 32 + l4 * 8);
    }
    #pragma unroll
    for (int m = 0; m < 4; ++m) {
      int px = m * 16 + l15;
      bf16x8 ax = {};
      #pragma unroll
      for (int j = 0; j < 8; ++j) {
        int t = l4 * 8 + j;
        if (t < 9) {
          int dyt = t / 3, dxt = t - dyt * 3;
          int xx = px + dxt - 1;
          float xv = ((unsigned)xx < 64u) ? x_lds[(mh + dyt) * 64 + xx] : 0.0f;
          ax[j] = f2bf(xv);
        }
      }
      #pragma unroll
      for (int j = 0; j < 4; ++j)
        acc[m][j] = __builtin_amdgcn_mfma_f32_16x16x32_bf16(ax, bx[j], acc[m][j], 0, 0, 0);
    }
  }

  readW(wfA, 0);   // stage-0 W frags

  // ---- pass 0: stages 0..17 ----
  #pragma unroll
  for (int i = 0; i < 18; ++i) {
    if ((i & 1) == 0) body(wfA, wfB, i);
    else              body(wfB, wfA, i);
  }

  // ---- pass 1 (layer-1 only): restage A with src1, stages 18..35 ----
  if (NSRC == 2) {
    __syncthreads();   // all a_lds reads done (also drains W loads 18,19 -> slots valid)
    stage_src<S1F32>(a_lds, src1, b, y0, tid);
    __syncthreads();
    #pragma unroll
    for (int i = 18; i < 36; ++i) {
      if ((i & 1) == 0) body(wfA, wfB, i);
      else              body(wfB, wfA, i);
    }
  }

  // ---- LSTM epilogue (lane-local gates) ----
  float bi[4];
  #pragma unroll
  for (int j = 0; j < 4; ++j) bi[j] = bias[j * 64 + g * 16 + l15];

  const int pix_base = b * 4096 + y0 * 64;
  const int f = g * 16 + l15;
  #pragma unroll
  for (int m = 0; m < 4; ++m) {
    #pragma unroll
    for (int r = 0; r < 4; ++r) {
      int pl = mh * 64 + m * 16 + l4 * 4 + r;
      int off = (pix_base + pl) * 64 + f;
      float zi = acc[m][0][r] + bi[0];
      float zf = acc[m][1][r] + bi[1];
      float zc = acc[m][2][r] + bi[2];
      float zo = acc[m][3][r] + bi[3];
      float ig = hsig(zi), fg = hsig(zf), og = hsig(zo);
      float cn = fg * c_old[off] + ig * tanhf(zc);
      float hn = og * tanhf(cn);
      c_out[off] = cn;
      h_out[off] = hn;
      if (hb_out) hb_out[off] = f2bf(hn);
    }
  }
}

// ---------------- 1x1 conv head ----------------
__global__ void frames_kernel(const float* __restrict__ h, const float* __restrict__ cw,
                              const float* __restrict__ cbp, float* __restrict__ out) {
  int tid = blockIdx.x * 256 + threadIdx.x;
  int p  = tid >> 2;
  int fc = (tid & 3) * 16;
  const float4* hp = reinterpret_cast<const float4*>(h + p * 64 + fc);
  const float4* wp = reinterpret_cast<const float4*>(cw + fc);
  float s = 0.0f;
  #pragma unroll
  for (int i = 0; i < 4; ++i) {
    float4 v = hp[i];
    float4 w = wp[i];
    s += v.x * w.x + v.y * w.y + v.z * w.z + v.w * w.w;
  }
  s += __shfl_xor(s, 1);
  s += __shfl_xor(s, 2);
  if ((tid & 3) == 0) out[p] = s + cbp[0];
}

// ---------------- launch ----------------
extern "C" void kernel_launch(void* const* d_in, const int* in_sizes, int n_in,
                              void* d_out, int out_size, void* d_ws, size_t ws_size,
                              hipStream_t stream) {
  const float* x   = (const float*)d_in[0];
  const float* h0  = (const float*)d_in[1];
  const float* c0  = (const float*)d_in[2];
  const float* h1  = (const float*)d_in[3];
  const float* c1  = (const float*)d_in[4];
  const float* k0  = (const float*)d_in[5];
  const float* rk0 = (const float*)d_in[6];
  const float* b0  = (const float*)d_in[7];
  const float* k1  = (const float*)d_in[8];
  const float* rk1 = (const float*)d_in[9];
  const float* b1  = (const float*)d_in[10];
  const float* cw  = (const float*)d_in[11];
  const float* cbp = (const float*)d_in[12];

  float* out    = (float*)d_out;
  float* frames = out;                       // [32,64,64,1]
  float* h0n    = out + 131072;              // [32,64,64,64]
  float* c0n    = out + 131072 + 8388608;
  float* h1n    = out + 131072 + 2 * 8388608;
  float* c1n    = out + 131072 + 3 * 8388608;

  char* ws = (char*)d_ws;
  const size_t SZ_H = 16777216;  // bytes per bf16 [32,64,64,64] buffer
  s16* h0nb = (s16*)(ws + 0 * SZ_H);
  s16* w0t  = (s16*)(ws + 1 * SZ_H);                 // rk0^T
  s16* w1t  = (s16*)(ws + 1 * SZ_H + 1 * 294912);    // k1^T
  s16* w2t  = (s16*)(ws + 1 * SZ_H + 2 * 294912);    // rk1^T
  s16* k0t  = (s16*)(ws + 1 * SZ_H + 3 * 294912);    // k0 padded [256][32]

  // prep (single launch)
  wprep_kernel<<<1760, 256, 0, stream>>>(rk0, k1, rk1, k0, w0t, w1t, w2t, k0t);

  // layer 0: z = conv(x,k0) + conv(h0,rk0) + b0   (h0 converted inline)
  cell_kernel<1, true, true, false><<<1024, 512, 0, stream>>>(
      h0, nullptr, w0t, nullptr, x, k0t, b0, c0, h0n, c0n, h0nb);

  // layer 1: z = conv(h0n,k1) + conv(h1,rk1) + b1  (h1 converted inline, 2 passes)
  cell_kernel<2, false, false, true><<<1024, 512, 0, stream>>>(
      h0nb, h1, w1t, w2t, nullptr, nullptr, b1, c1, h1n, c1n, nullptr);

  // head
  frames_kernel<<<2048, 256, 0, stream>>>(h1n, cw, cbp, frames);
}

// Round 6
// 206.477 us; speedup vs baseline: 1.6699x; 1.6699x over previous
//
#include <hip/hip_runtime.h>
#include <hip/hip_bf16.h>

typedef short s16;
typedef __attribute__((ext_vector_type(8))) short bf16x8;  // 8 bf16 = 4 VGPR (MFMA A/B frag)
typedef __attribute__((ext_vector_type(4))) float f32x4;   // MFMA C/D frag

// ---------------- helpers ----------------
__device__ __forceinline__ s16 f2bf(float f) {
  unsigned u = __builtin_bit_cast(unsigned, f);
  unsigned r = (u + 0x7FFFu + ((u >> 16) & 1u)) >> 16;
  return (s16)r;
}

__device__ __forceinline__ float hsig(float x) {
  return fminf(fmaxf(0.2f * x + 0.5f, 0.0f), 1.0f);
}

// ---------------- prep kernel ----------------
// Weight shuffle into LANE-DIRECT layout:
//   wq[tap*2+k][j][g][lane][8]  (stage slice = 8192 elem = 16 KB)
// where lane = l4*16+l15, oc = j*64+g*16+l15, ic = k*32+l4*8+e.
// In-kernel read: frag j = 16B at wq + stage*8192 + j*2048 + g*512 + lane*8
// -> 64 consecutive lanes read 1 KB contiguous (perfect coalescing).
__global__ void wprep_kernel(const float* __restrict__ rk0, const float* __restrict__ k1,
                             const float* __restrict__ rk1, const float* __restrict__ k0,
                             s16* __restrict__ w0q, s16* __restrict__ w1q,
                             s16* __restrict__ w2q, s16* __restrict__ k0t) {
  int idx = blockIdx.x * 256 + threadIdx.x;
  const int n1 = 9 * 2 * 4 * 4 * 512;  // 147456
  if (idx < 3 * n1) {
    int which = idx / n1;
    int i = idx - which * n1;
    int e    = i & 7;
    int lane = (i >> 3) & 63;
    int g    = (i >> 9) & 3;
    int j    = (i >> 11) & 3;
    int k    = (i >> 13) & 1;
    int tap  = i >> 14;
    int l15 = lane & 15, l4 = lane >> 4;
    int ic = k * 32 + l4 * 8 + e;
    int oc = j * 64 + g * 16 + l15;
    const float* src = (which == 0) ? rk0 : (which == 1) ? k1 : rk1;
    s16* dst = (which == 0) ? w0q : (which == 1) ? w1q : w2q;
    dst[i] = f2bf(src[(tap * 64 + ic) * 256 + oc]);
  } else if (idx < 3 * n1 + 8192) {
    int r = idx - 3 * n1;
    int kk = r & 31;
    int oc = r >> 5;
    k0t[r] = (kk < 9) ? f2bf(k0[kk * 256 + oc]) : (s16)0;
  }
}

// ---------------- ConvLSTM cell kernel ----------------
// Block: 512 threads = 8 waves, 2 blocks/CU (layer-1 LDS 67.6 KB). Tile: M=128
// pixels (2 output rows), N=256 (all 4 gates). Wave (mh = wave>>2, g = wave&3).
// ZERO barriers in the K-loop: A tiles (both sources) staged once in LDS
// (XOR-swizzled, x-padded stride 66); weights read per-lane directly from
// global in the lane-direct wq layout, register double-buffered (wfA/wfB,
// prefetch distance ~1 stage). Waves run fully decoupled; latency hidden by
// ILP + 4 waves/SIMD TLP.
// grid: 1024 blocks: b = blk>>5, y0 = (blk&31)*2.
#define PXS 66
#define ROWSZ (PXS * 64)             // 4224 elements per tile row
#define ASZ (4 * ROWSZ)              // 16896 elements (one source tile, 4 rows)

template <bool F32>
__device__ __forceinline__ bf16x8 load_conv8(const void* src, long off) {
  if constexpr (F32) {
    const float* p = (const float*)src + off;
    float4 v0 = *reinterpret_cast<const float4*>(p);
    float4 v1 = *reinterpret_cast<const float4*>(p + 4);
    bf16x8 r;
    r[0] = f2bf(v0.x); r[1] = f2bf(v0.y); r[2] = f2bf(v0.z); r[3] = f2bf(v0.w);
    r[4] = f2bf(v1.x); r[5] = f2bf(v1.y); r[6] = f2bf(v1.z); r[7] = f2bf(v1.w);
    return r;
  } else {
    return *reinterpret_cast<const bf16x8*>((const s16*)src + off);
  }
}

template <bool F32>
__device__ __forceinline__ void stage_src(s16* a_lds, const void* src, int b, int y0, int tid) {
  #pragma unroll
  for (int i = 0; i < 4; ++i) {
    int c   = tid + i * 512;        // 0..2047 16B-chunks
    int row = c >> 9;               // 0..3
    int px  = (c >> 3) & 63;
    int cb  = c & 7;
    int y   = y0 - 1 + row;
    int xp  = px + 1;
    bf16x8 v = {};
    if ((unsigned)y < 64u)
      v = load_conv8<F32>(src, ((long)(b * 64 + y) * 64 + px) * 64 + cb * 8);
    *reinterpret_cast<bf16x8*>(a_lds + (row * PXS + xp) * 64 + ((cb ^ (xp & 7)) * 8)) = v;
  }
  // zero x-border columns (xp = 0, 65)
  if (tid < 64) {
    int row = tid >> 4;
    int xp  = ((tid >> 3) & 1) ? 65 : 0;
    int cb  = tid & 7;
    bf16x8 z = {};
    *reinterpret_cast<bf16x8*>(a_lds + (row * PXS + xp) * 64 + cb * 8) = z;
  }
}

template <int NSRC, bool XPATH, bool S0F32, bool S1F32>
__global__ __launch_bounds__(512, 4) void cell_kernel(
    const void* __restrict__ src0,  // [B,64,64,64] bf16 or fp32
    const void* __restrict__ src1,  // [B,64,64,64] bf16 or fp32 (NSRC==2)
    const s16* __restrict__ w0,     // wq layout [18][8192] bf16
    const s16* __restrict__ w1,     // wq layout (NSRC==2)
    const float* __restrict__ xin,  // [B,64,64] fp32 (XPATH)
    const s16* __restrict__ k0t,    // [256][32] bf16 (XPATH)
    const float* __restrict__ bias, // [256]
    const float* __restrict__ c_old,// [B,64,64,64] fp32
    float* __restrict__ h_out,
    float* __restrict__ c_out,
    s16* __restrict__ hb_out)       // bf16 copy of h (nullable)
{
  __shared__ __align__(16) s16 a_lds[NSRC * ASZ];   // 33.8 KB per source
  __shared__ float x_lds[XPATH ? 256 : 1];

  const int tid = threadIdx.x;
  const int b  = blockIdx.x >> 5;
  const int y0 = (blockIdx.x & 31) << 1;

  // ---- stage A tiles once (rows y0-1 .. y0+2, zero-padded) ----
  stage_src<S0F32>(a_lds, src0, b, y0, tid);
  if (NSRC == 2) stage_src<S1F32>(a_lds + ASZ, src1, b, y0, tid);
  if (XPATH) {
    if (tid < 256) {
      int row = tid >> 6, px = tid & 63;
      int y = y0 - 1 + row;
      x_lds[tid] = ((unsigned)y < 64u) ? xin[(b * 64 + y) * 64 + px] : 0.0f;
    }
  }
  __syncthreads();   // the only block-wide sync

  const int wave = tid >> 6;
  const int lane = tid & 63;
  const int g    = wave & 3;
  const int mh   = wave >> 2;   // 0..1: output row within the 2-row tile
  const int l15  = lane & 15;
  const int l4   = lane >> 4;

  constexpr int NST = NSRC * 18;

  f32x4 acc[4][4] = {};  // [m-frag][gate j]

  // ---- x-conv as one zero-padded K=32 MFMA step (layer 0 only) ----
  if (XPATH) {
    bf16x8 bx[4];
    #pragma unroll
    for (int j = 0; j < 4; ++j) {
      int oc = j * 64 + g * 16 + l15;
      bx[j] = *reinterpret_cast<const bf16x8*>(k0t + oc * 32 + l4 * 8);
    }
    #pragma unroll
    for (int m = 0; m < 4; ++m) {
      int px = m * 16 + l15;
      bf16x8 ax = {};
      #pragma unroll
      for (int j = 0; j < 8; ++j) {
        int t = l4 * 8 + j;
        if (t < 9) {
          int dyt = t / 3, dxt = t - dyt * 3;
          int xx = px + dxt - 1;
          float xv = ((unsigned)xx < 64u) ? x_lds[(mh + dyt) * 64 + xx] : 0.0f;
          ax[j] = f2bf(xv);
        }
      }
      #pragma unroll
      for (int j = 0; j < 4; ++j)
        acc[m][j] = __builtin_amdgcn_mfma_f32_16x16x32_bf16(ax, bx[j], acc[m][j], 0, 0, 0);
    }
  }

  // ---- W fragment load: 4 coalesced 16B global loads per stage ----
  const int wl_off = g * 512 + lane * 8;
  auto loadW = [&](bf16x8 (&wf)[4], int u) {
    int si = (NSRC == 2 && u >= 18) ? 1 : 0;
    const s16* wp = (si ? w1 : w0) + (u - 18 * si) * 8192 + wl_off;
    #pragma unroll
    for (int j = 0; j < 4; ++j)
      wf[j] = *reinterpret_cast<const bf16x8*>(wp + j * 2048);
  };

  auto doStage = [&](const bf16x8 (&wf)[4], int u) {  // u compile-time via unroll
    int si = (NSRC == 2 && u >= 18) ? 1 : 0;
    int uu = u - 18 * si;
    int tap = uu >> 1, kk = uu & 1;
    int dy = tap / 3, dx = tap - dy * 3;
    const char* lb = (const char*)a_lds + (si * ASZ + (mh + dy) * ROWSZ) * 2;
    #pragma unroll
    for (int m = 0; m < 4; ++m) {
      int xq   = m * 16 + l15 + dx;
      int boff = xq * 128 + (((kk << 6) | (l4 << 4)) ^ ((xq & 7) << 4));
      bf16x8 a = *reinterpret_cast<const bf16x8*>(lb + boff);
      #pragma unroll
      for (int j = 0; j < 4; ++j)
        acc[m][j] = __builtin_amdgcn_mfma_f32_16x16x32_bf16(a, wf[j], acc[m][j], 0, 0, 0);
    }
  };

  // ---- main K loop: no barriers, register double-buffered W ----
  bf16x8 wfA[4], wfB[4];
  loadW(wfA, 0);
  loadW(wfB, 1);
  #pragma unroll
  for (int u = 0; u < NST; u += 2) {
    doStage(wfA, u);
    if (u + 2 < NST) loadW(wfA, u + 2);
    doStage(wfB, u + 1);
    if (u + 3 < NST) loadW(wfB, u + 3);
  }

  // ---- LSTM epilogue (lane-local gates) ----
  float bi[4];
  #pragma unroll
  for (int j = 0; j < 4; ++j) bi[j] = bias[j * 64 + g * 16 + l15];

  const int pix_base = b * 4096 + y0 * 64;
  const int f = g * 16 + l15;
  #pragma unroll
  for (int m = 0; m < 4; ++m) {
    #pragma unroll
    for (int r = 0; r < 4; ++r) {
      int pl = mh * 64 + m * 16 + l4 * 4 + r;
      int off = (pix_base + pl) * 64 + f;
      float zi = acc[m][0][r] + bi[0];
      float zf = acc[m][1][r] + bi[1];
      float zc = acc[m][2][r] + bi[2];
      float zo = acc[m][3][r] + bi[3];
      float ig = hsig(zi), fg = hsig(zf), og = hsig(zo);
      float cn = fg * c_old[off] + ig * tanhf(zc);
      float hn = og * tanhf(cn);
      c_out[off] = cn;
      h_out[off] = hn;
      if (hb_out) hb_out[off] = f2bf(hn);
    }
  }
}

// ---------------- 1x1 conv head ----------------
__global__ void frames_kernel(const float* __restrict__ h, const float* __restrict__ cw,
                              const float* __restrict__ cbp, float* __restrict__ out) {
  int tid = blockIdx.x * 256 + threadIdx.x;
  int p  = tid >> 2;
  int fc = (tid & 3) * 16;
  const float4* hp = reinterpret_cast<const float4*>(h + p * 64 + fc);
  const float4* wp = reinterpret_cast<const float4*>(cw + fc);
  float s = 0.0f;
  #pragma unroll
  for (int i = 0; i < 4; ++i) {
    float4 v = hp[i];
    float4 w = wp[i];
    s += v.x * w.x + v.y * w.y + v.z * w.z + v.w * w.w;
  }
  s += __shfl_xor(s, 1);
  s += __shfl_xor(s, 2);
  if ((tid & 3) == 0) out[p] = s + cbp[0];
}

// ---------------- launch ----------------
extern "C" void kernel_launch(void* const* d_in, const int* in_sizes, int n_in,
                              void* d_out, int out_size, void* d_ws, size_t ws_size,
                              hipStream_t stream) {
  const float* x   = (const float*)d_in[0];
  const float* h0  = (const float*)d_in[1];
  const float* c0  = (const float*)d_in[2];
  const float* h1  = (const float*)d_in[3];
  const float* c1  = (const float*)d_in[4];
  const float* k0  = (const float*)d_in[5];
  const float* rk0 = (const float*)d_in[6];
  const float* b0  = (const float*)d_in[7];
  const float* k1  = (const float*)d_in[8];
  const float* rk1 = (const float*)d_in[9];
  const float* b1  = (const float*)d_in[10];
  const float* cw  = (const float*)d_in[11];
  const float* cbp = (const float*)d_in[12];

  float* out    = (float*)d_out;
  float* frames = out;                       // [32,64,64,1]
  float* h0n    = out + 131072;              // [32,64,64,64]
  float* c0n    = out + 131072 + 8388608;
  float* h1n    = out + 131072 + 2 * 8388608;
  float* c1n    = out + 131072 + 3 * 8388608;

  char* ws = (char*)d_ws;
  const size_t SZ_H = 16777216;  // bytes per bf16 [32,64,64,64] buffer
  s16* h0nb = (s16*)(ws + 0 * SZ_H);
  s16* w0q  = (s16*)(ws + 1 * SZ_H);                 // rk0 shuffled
  s16* w1q  = (s16*)(ws + 1 * SZ_H + 1 * 294912);    // k1 shuffled
  s16* w2q  = (s16*)(ws + 1 * SZ_H + 2 * 294912);    // rk1 shuffled
  s16* k0t  = (s16*)(ws + 1 * SZ_H + 3 * 294912);    // k0 padded [256][32]

  // prep (single launch)
  wprep_kernel<<<1760, 256, 0, stream>>>(rk0, k1, rk1, k0, w0q, w1q, w2q, k0t);

  // layer 0: z = conv(x,k0) + conv(h0,rk0) + b0   (h0 converted inline)
  cell_kernel<1, true, true, false><<<1024, 512, 0, stream>>>(
      h0, nullptr, w0q, nullptr, x, k0t, b0, c0, h0n, c0n, h0nb);

  // layer 1: z = conv(h0n,k1) + conv(h1,rk1) + b1  (h1 converted inline)
  cell_kernel<2, false, false, true><<<1024, 512, 0, stream>>>(
      h0nb, h1, w1q, w2q, nullptr, nullptr, b1, c1, h1n, c1n, nullptr);

  // head
  frames_kernel<<<2048, 256, 0, stream>>>(h1n, cw, cbp, frames);
}